// Round 1
// baseline (723.702 us; speedup 1.0000x reference)
//
#include <hip/hip_runtime.h>

#define MDIM 8192
#define NDIM 1024
#define FIN  1024
#define DP1  11
#define KDIM 12288   // FIN * 12  (11 chebyshev + 1 linear slot per feature)
#define BM 128
#define BN 128
#define BK 32

typedef __attribute__((ext_vector_type(8))) short short8;
typedef __attribute__((ext_vector_type(4))) float float4v;

typedef const __attribute__((address_space(1))) unsigned int* gptr_t;
typedef __attribute__((address_space(3))) unsigned int* lptr_t;

__device__ __forceinline__ unsigned short f2bf(float f) {
  unsigned int u = __float_as_uint(f);
  u += 0x7FFFu + ((u >> 16) & 1u);   // round-to-nearest-even
  return (unsigned short)(u >> 16);
}

// ---------------- A prep: A[b][i*12+n] = T_n(tanh(x)), slot 11 = x ----------
__global__ __launch_bounds__(256) void prep_A_kernel(const float* __restrict__ x,
                                                     unsigned short* __restrict__ A) {
  int gid = blockIdx.x * 256 + threadIdx.x;   // gid = b*1024 + i
  float xv = x[gid];
  float t = tanhf(xv);
  unsigned short o[12];
  o[0] = 0x3F80u;          // 1.0f
  o[1] = f2bf(t);
  float tm2 = 1.f, tm1 = t;
#pragma unroll
  for (int n = 2; n <= 10; n++) {
    float cur = 2.f * t * tm1 - tm2;
    o[n] = f2bf(cur);
    tm2 = tm1; tm1 = cur;
  }
  o[11] = f2bf(xv);
  ushort4* dst = (ushort4*)(A + (size_t)gid * 12);   // 24*gid bytes, 8B aligned
  dst[0] = make_ushort4(o[0], o[1], o[2],  o[3]);
  dst[1] = make_ushort4(o[4], o[5], o[6],  o[7]);
  dst[2] = make_ushort4(o[8], o[9], o[10], o[11]);
}

// ---- B prep (K-major): Bt[o][i*12+n] = mean + eps*exp(0.5*lv); slot 11 = W;
// ---- fused KL reduction -----------------------------------------------------
__global__ __launch_bounds__(256) void prep_B_kernel(const float* __restrict__ mean,
    const float* __restrict__ lv, const float* __restrict__ W,
    const float* __restrict__ eps, unsigned short* __restrict__ Bt,
    float* __restrict__ kl_out) {
  int gid = blockIdx.x * 256 + threadIdx.x;   // gid = i*1024 + o
  int i = gid >> 10;
  int o = gid & 1023;
  size_t base = (size_t)gid * DP1;
  unsigned short out[12];
  float klp = 0.f;
#pragma unroll
  for (int n = 0; n < DP1; n++) {
    float m = mean[base + n];
    float l = lv[base + n];
    float e = eps[base + n];
    out[n] = f2bf(fmaf(e, expf(0.5f * l), m));
    klp += expf(l) + m * m - 1.f - l;
  }
  out[11] = f2bf(W[gid]);
  ushort4* dst = (ushort4*)(Bt + (size_t)o * KDIM + (size_t)i * 12);
  dst[0] = make_ushort4(out[0], out[1], out[2],  out[3]);
  dst[1] = make_ushort4(out[4], out[5], out[6],  out[7]);
  dst[2] = make_ushort4(out[8], out[9], out[10], out[11]);
  // wave-64 shuffle reduce, one atomic per wave
#pragma unroll
  for (int off = 32; off > 0; off >>= 1) klp += __shfl_down(klp, off, 64);
  if ((threadIdx.x & 63) == 0) atomicAdd(kl_out, 0.5f * klp);
}

// ---------------- GEMM: C = A(MxK) * Bt(NxK)^T, bf16 MFMA 16x16x32 ----------
__global__ __launch_bounds__(256, 2) void gemm_kernel(const unsigned short* __restrict__ A,
    const unsigned short* __restrict__ Bt, float* __restrict__ C) {
  __shared__ unsigned short As[BM * BK];   // row-major [128][32]
  __shared__ unsigned short Bs[BN * BK];   // [n][k] row-major [128][32]
  const int tid  = threadIdx.x;
  const int lane = tid & 63;
  const int wid  = tid >> 6;
  const int bx   = blockIdx.x;
  const int bm0  = (bx >> 3) * BM;
  const int bn0  = (bx & 7) * BN;
  const int wm   = (wid >> 1) * 64;
  const int wn   = (wid & 1) * 64;
  const int q    = lane >> 4;
  const int r    = lane & 15;

  float4v acc[4][4];
#pragma unroll
  for (int a = 0; a < 4; a++)
#pragma unroll
    for (int b = 0; b < 4; b++) acc[a][b] = (float4v){0.f, 0.f, 0.f, 0.f};

  const int f0 = tid, f1 = tid + 256;            // 512 x 16B covers one 8KB tile
  const char* gA = (const char*)(A  + (size_t)bm0 * KDIM);
  const char* gB = (const char*)(Bt + (size_t)bn0 * KDIM);
  const size_t offA0 = (size_t)(f0 >> 2) * (KDIM * 2) + (size_t)(f0 & 3) * 16;
  const size_t offA1 = (size_t)(f1 >> 2) * (KDIM * 2) + (size_t)(f1 & 3) * 16;
  char* ldsA = (char*)As;
  char* ldsB = (char*)Bs;

  for (int k0 = 0; k0 < KDIM; k0 += BK) {
    const size_t kb = (size_t)k0 * 2;
    __builtin_amdgcn_global_load_lds((gptr_t)(gA + offA0 + kb), (lptr_t)(ldsA + f0 * 16), 16, 0, 0);
    __builtin_amdgcn_global_load_lds((gptr_t)(gA + offA1 + kb), (lptr_t)(ldsA + f1 * 16), 16, 0, 0);
    __builtin_amdgcn_global_load_lds((gptr_t)(gB + offA0 + kb), (lptr_t)(ldsB + f0 * 16), 16, 0, 0);
    __builtin_amdgcn_global_load_lds((gptr_t)(gB + offA1 + kb), (lptr_t)(ldsB + f1 * 16), 16, 0, 0);
    __syncthreads();

    short8 af[4], bf[4];
#pragma unroll
    for (int t = 0; t < 4; t++) {
      af[t] = *(const short8*)(ldsA + ((wm + t * 16 + r) * 64 + q * 16));
      bf[t] = *(const short8*)(ldsB + ((wn + t * 16 + r) * 64 + q * 16));
    }
#pragma unroll
    for (int mt = 0; mt < 4; mt++)
#pragma unroll
      for (int nt = 0; nt < 4; nt++)
        acc[mt][nt] = __builtin_amdgcn_mfma_f32_16x16x32_bf16(af[mt], bf[nt], acc[mt][nt], 0, 0, 0);
    __syncthreads();
  }

  float* Cb = C + (size_t)(bm0 + wm) * NDIM + (bn0 + wn);
#pragma unroll
  for (int mt = 0; mt < 4; mt++)
#pragma unroll
    for (int nt = 0; nt < 4; nt++)
#pragma unroll
      for (int v = 0; v < 4; v++)
        Cb[(size_t)(mt * 16 + q * 4 + v) * NDIM + (nt * 16 + r)] = acc[mt][nt][v];
}

extern "C" void kernel_launch(void* const* d_in, const int* in_sizes, int n_in,
                              void* d_out, int out_size, void* d_ws, size_t ws_size,
                              hipStream_t stream) {
  const float* x    = (const float*)d_in[0];   // [8192,1024]
  const float* mean = (const float*)d_in[1];   // [1024,1024,11]
  const float* lv   = (const float*)d_in[2];   // [1024,1024,11]
  const float* W    = (const float*)d_in[3];   // [1024,1024]
  const float* eps  = (const float*)d_in[4];   // [1,1024,1024,11]
  float* out = (float*)d_out;                  // [8192*1024] + [1] kl

  unsigned short* A  = (unsigned short*)d_ws;              // 8192*12288 bf16 = 192 MB
  unsigned short* Bt = A + (size_t)MDIM * KDIM;            // 1024*12288 bf16 = 24 MB
  float* kl = out + (size_t)MDIM * NDIM;

  hipMemsetAsync(kl, 0, sizeof(float), stream);
  prep_A_kernel<<<MDIM * FIN / 256, 256, 0, stream>>>(x, A);
  prep_B_kernel<<<FIN * NDIM / 256, 256, 0, stream>>>(mean, lv, W, eps, Bt, kl);
  gemm_kernel<<<(MDIM / BM) * (NDIM / BN), 256, 0, stream>>>(A, Bt, out);
}

// Round 3
// 626.417 us; speedup vs baseline: 1.1553x; 1.1553x over previous
//
#include <hip/hip_runtime.h>

#define MDIM 8192
#define NDIM 1024
#define FIN  1024
#define DP1  11
#define KDIM 12288   // FIN * 12  (11 chebyshev + 1 linear slot per feature)
#define BM 128
#define BN 128
#define BK 32

typedef __attribute__((ext_vector_type(8))) short short8;
typedef __attribute__((ext_vector_type(4))) float float4v;

typedef const __attribute__((address_space(1))) unsigned int* gptr_t;
typedef __attribute__((address_space(3))) unsigned int* lptr_t;

__device__ __forceinline__ unsigned short f2bf(float f) {
  unsigned int u = __float_as_uint(f);
  u += 0x7FFFu + ((u >> 16) & 1u);   // round-to-nearest-even
  return (unsigned short)(u >> 16);
}

// fast tanh via hardware exp: tanh(x) = 1 - 2/(e^{2x}+1); inf-safe at both ends
__device__ __forceinline__ float fast_tanh(float x) {
  float e = __expf(2.f * x);
  return 1.f - 2.f / (e + 1.f);
}

// ---------------- A prep: A[b][i*12+n] = T_n(tanh(x)), slot 11 = x ----------
__global__ __launch_bounds__(256) void prep_A_kernel(const float* __restrict__ x,
                                                     unsigned short* __restrict__ A) {
  __shared__ unsigned short sb[256 * 12];   // 6 KB staging for coalesced stores
  const int tid = threadIdx.x;
  const int gid = blockIdx.x * 256 + tid;   // gid = b*1024 + i
  float xv = x[gid];
  float t = fast_tanh(xv);
  unsigned short o[12];
  o[0] = 0x3F80u;          // 1.0f
  o[1] = f2bf(t);
  float tm2 = 1.f, tm1 = t;
#pragma unroll
  for (int n = 2; n <= 10; n++) {
    float cur = 2.f * t * tm1 - tm2;
    o[n] = f2bf(cur);
    tm2 = tm1; tm1 = cur;
  }
  o[11] = f2bf(xv);
  ushort4* d = (ushort4*)&sb[tid * 12];     // 24B per thread, 8B aligned
  d[0] = make_ushort4(o[0], o[1], o[2],  o[3]);
  d[1] = make_ushort4(o[4], o[5], o[6],  o[7]);
  d[2] = make_ushort4(o[8], o[9], o[10], o[11]);
  __syncthreads();
  // 6144 B = 384 x 16B chunks, fully coalesced
  float4* dst = (float4*)(A + (size_t)blockIdx.x * 256 * 12);
  const float4* s = (const float4*)sb;
  dst[tid] = s[tid];
  if (tid < 128) dst[256 + tid] = s[256 + tid];
}

// ---- B prep (K-major): Bt[o][i*12+n] = mean + eps*exp(0.5*lv); slot 11 = W;
// ---- KL partial per block (no device atomics) -------------------------------
__global__ __launch_bounds__(256) void prep_B_kernel(const float* __restrict__ mean,
    const float* __restrict__ lv, const float* __restrict__ W,
    const float* __restrict__ eps, unsigned short* __restrict__ Bt,
    float* __restrict__ partial) {
  __shared__ float wsum[4];
  const int tid = threadIdx.x;
  const int gid = blockIdx.x * 256 + tid;   // gid = i*1024 + o
  const int i = gid >> 10;
  const int o = gid & 1023;
  size_t base = (size_t)gid * DP1;
  unsigned short out[12];
  float klp = 0.f;
#pragma unroll
  for (int n = 0; n < DP1; n++) {
    float m = mean[base + n];
    float l = lv[base + n];
    float e = eps[base + n];
    float sd = __expf(0.5f * l);
    out[n] = f2bf(fmaf(e, sd, m));
    klp += sd * sd + m * m - 1.f - l;   // exp(l) == sd^2
  }
  out[11] = f2bf(W[gid]);
  ushort4* dst = (ushort4*)(Bt + (size_t)o * KDIM + (size_t)i * 12);
  dst[0] = make_ushort4(out[0], out[1], out[2],  out[3]);
  dst[1] = make_ushort4(out[4], out[5], out[6],  out[7]);
  dst[2] = make_ushort4(out[8], out[9], out[10], out[11]);
#pragma unroll
  for (int off = 32; off > 0; off >>= 1) klp += __shfl_down(klp, off, 64);
  if ((tid & 63) == 0) wsum[tid >> 6] = klp;
  __syncthreads();
  if (tid == 0) partial[blockIdx.x] = wsum[0] + wsum[1] + wsum[2] + wsum[3];
}

__global__ __launch_bounds__(256) void reduce_kl_kernel(const float* __restrict__ partial,
                                                        float* __restrict__ kl_out) {
  __shared__ float wsum[4];
  const int tid = threadIdx.x;
  float s = 0.f;
  for (int idx = tid; idx < 4096; idx += 256) s += partial[idx];
#pragma unroll
  for (int off = 32; off > 0; off >>= 1) s += __shfl_down(s, off, 64);
  if ((tid & 63) == 0) wsum[tid >> 6] = s;
  __syncthreads();
  if (tid == 0) kl_out[0] = 0.5f * (wsum[0] + wsum[1] + wsum[2] + wsum[3]);
}

// ---------------- GEMM: C = A(MxK) * Bt(NxK)^T, bf16 MFMA 16x16x32 ----------
// Double-buffered single-barrier K-loop; XOR-swizzled LDS chunk placement.
__global__ __launch_bounds__(256, 2) void gemm_kernel(const unsigned short* __restrict__ A,
    const unsigned short* __restrict__ Bt, float* __restrict__ C) {
  __shared__ unsigned short As[2][BM * BK];   // 2 x 8KB
  __shared__ unsigned short Bs[2][BN * BK];
  const int tid  = threadIdx.x;
  const int lane = tid & 63;
  const int wid  = tid >> 6;
  const int bm0  = (blockIdx.x >> 3) * BM;
  const int bn0  = (blockIdx.x & 7) * BN;
  const int wm   = (wid >> 1) * 64;
  const int wn   = (wid & 1) * 64;
  const int q    = lane >> 4;
  const int r    = lane & 15;
  // swizzle: logical chunk q of row `row` lives at physical chunk q ^ ((row^(row>>2))&3);
  // for row = base16 + r this equals q ^ ((r^(r>>2))&3)  -> 2-way banks max (free)
  const int cph  = (q ^ ((r ^ (r >> 2)) & 3)) * 16;   // byte offset within row

  float4v acc[4][4];
#pragma unroll
  for (int a = 0; a < 4; a++)
#pragma unroll
    for (int b = 0; b < 4; b++) acc[a][b] = (float4v){0.f, 0.f, 0.f, 0.f};

  // staging: lane f writes LDS phys chunk f (16B); fetch the swizzled logical chunk
  const int f0 = tid, f1 = tid + 256;
  const int row0 = f0 >> 2, row1 = f1 >> 2;
  const int kc0 = (f0 & 3) ^ ((row0 ^ (row0 >> 2)) & 3);
  const int kc1 = (f1 & 3) ^ ((row1 ^ (row1 >> 2)) & 3);
  const char* gA = (const char*)(A  + (size_t)bm0 * KDIM);
  const char* gB = (const char*)(Bt + (size_t)bn0 * KDIM);
  const size_t oA0 = (size_t)row0 * (KDIM * 2) + (size_t)kc0 * 16;
  const size_t oA1 = (size_t)row1 * (KDIM * 2) + (size_t)kc1 * 16;
  const int l0 = f0 * 16, l1 = f1 * 16;

  // prologue: tile 0 -> buf 0
  __builtin_amdgcn_global_load_lds((gptr_t)(gA + oA0), (lptr_t)((char*)As[0] + l0), 16, 0, 0);
  __builtin_amdgcn_global_load_lds((gptr_t)(gA + oA1), (lptr_t)((char*)As[0] + l1), 16, 0, 0);
  __builtin_amdgcn_global_load_lds((gptr_t)(gB + oA0), (lptr_t)((char*)Bs[0] + l0), 16, 0, 0);
  __builtin_amdgcn_global_load_lds((gptr_t)(gB + oA1), (lptr_t)((char*)Bs[0] + l1), 16, 0, 0);

  int cur = 0;
  for (int k0 = 0; k0 < KDIM; k0 += BK) {
    __syncthreads();   // drains vmcnt(0): buf[cur] ready; buf[cur^1] safe to overwrite
    if (k0 + BK < KDIM) {
      const size_t kb = (size_t)(k0 + BK) * 2;
      const int nxt = cur ^ 1;
      __builtin_amdgcn_global_load_lds((gptr_t)(gA + oA0 + kb), (lptr_t)((char*)As[nxt] + l0), 16, 0, 0);
      __builtin_amdgcn_global_load_lds((gptr_t)(gA + oA1 + kb), (lptr_t)((char*)As[nxt] + l1), 16, 0, 0);
      __builtin_amdgcn_global_load_lds((gptr_t)(gB + oA0 + kb), (lptr_t)((char*)Bs[nxt] + l0), 16, 0, 0);
      __builtin_amdgcn_global_load_lds((gptr_t)(gB + oA1 + kb), (lptr_t)((char*)Bs[nxt] + l1), 16, 0, 0);
    }
    const char* la = (const char*)As[cur];
    const char* lb = (const char*)Bs[cur];
    short8 af[4], bg[4];
#pragma unroll
    for (int t = 0; t < 4; t++) {
      af[t] = *(const short8*)(la + (wm + t * 16 + r) * 64 + cph);
      bg[t] = *(const short8*)(lb + (wn + t * 16 + r) * 64 + cph);
    }
#pragma unroll
    for (int mt = 0; mt < 4; mt++)
#pragma unroll
      for (int nt = 0; nt < 4; nt++)
        acc[mt][nt] = __builtin_amdgcn_mfma_f32_16x16x32_bf16(af[mt], bg[nt], acc[mt][nt], 0, 0, 0);
    cur ^= 1;
  }

  float* Cb = C + (size_t)(bm0 + wm) * NDIM + (bn0 + wn);
#pragma unroll
  for (int mt = 0; mt < 4; mt++)
#pragma unroll
    for (int nt = 0; nt < 4; nt++)
#pragma unroll
      for (int v = 0; v < 4; v++)
        Cb[(size_t)(mt * 16 + q * 4 + v) * NDIM + (nt * 16 + r)] = acc[mt][nt][v];
}

extern "C" void kernel_launch(void* const* d_in, const int* in_sizes, int n_in,
                              void* d_out, int out_size, void* d_ws, size_t ws_size,
                              hipStream_t stream) {
  const float* x    = (const float*)d_in[0];   // [8192,1024]
  const float* mean = (const float*)d_in[1];   // [1024,1024,11]
  const float* lv   = (const float*)d_in[2];   // [1024,1024,11]
  const float* W    = (const float*)d_in[3];   // [1024,1024]
  const float* eps  = (const float*)d_in[4];   // [1,1024,1024,11]
  float* out = (float*)d_out;                  // [8192*1024] + [1] kl

  unsigned short* A  = (unsigned short*)d_ws;              // 192 MB
  unsigned short* Bt = A + (size_t)MDIM * KDIM;            // 24 MB
  float* kl = out + (size_t)MDIM * NDIM;
  // KL partials live in the head of d_out; GEMM overwrites them afterwards.
  float* partial = out;

  prep_A_kernel<<<MDIM * FIN / 256, 256, 0, stream>>>(x, A);
  prep_B_kernel<<<FIN * NDIM / 256, 256, 0, stream>>>(mean, lv, W, eps, Bt, partial);
  reduce_kl_kernel<<<1, 256, 0, stream>>>(partial, kl);
  gemm_kernel<<<(MDIM / BM) * (NDIM / BN), 256, 0, stream>>>(A, Bt, out);
}

// Round 4
// 563.962 us; speedup vs baseline: 1.2832x; 1.1107x over previous
//
#include <hip/hip_runtime.h>

#define MDIM 8192
#define NDIM 1024
#define FIN  1024
#define DP1  11
#define KDIM 12288   // FIN * 12  (11 chebyshev + 1 linear slot per feature)
#define BK 32

typedef __attribute__((ext_vector_type(8))) short short8;
typedef __attribute__((ext_vector_type(4))) float float4v;

typedef const __attribute__((address_space(1))) unsigned int* gptr_t;
typedef __attribute__((address_space(3))) unsigned int* lptr_t;

__device__ __forceinline__ unsigned short f2bf(float f) {
  unsigned int u = __float_as_uint(f);
  u += 0x7FFFu + ((u >> 16) & 1u);   // round-to-nearest-even
  return (unsigned short)(u >> 16);
}

// fast tanh via hardware exp: tanh(x) = 1 - 2/(e^{2x}+1); inf-safe at both ends
__device__ __forceinline__ float fast_tanh(float x) {
  float e = __expf(2.f * x);
  return 1.f - 2.f / (e + 1.f);
}

// ---------------- A prep: A[b][i*12+n] = T_n(tanh(x)), slot 11 = x ----------
__global__ __launch_bounds__(256) void prep_A_kernel(const float* __restrict__ x,
                                                     unsigned short* __restrict__ A) {
  __shared__ unsigned short sb[256 * 12];   // 6 KB staging for coalesced stores
  const int tid = threadIdx.x;
  const int gid = blockIdx.x * 256 + tid;   // gid = b*1024 + i
  float xv = x[gid];
  float t = fast_tanh(xv);
  unsigned short o[12];
  o[0] = 0x3F80u;          // 1.0f
  o[1] = f2bf(t);
  float tm2 = 1.f, tm1 = t;
#pragma unroll
  for (int n = 2; n <= 10; n++) {
    float cur = 2.f * t * tm1 - tm2;
    o[n] = f2bf(cur);
    tm2 = tm1; tm1 = cur;
  }
  o[11] = f2bf(xv);
  ushort4* d = (ushort4*)&sb[tid * 12];     // 24B per thread, 8B aligned
  d[0] = make_ushort4(o[0], o[1], o[2],  o[3]);
  d[1] = make_ushort4(o[4], o[5], o[6],  o[7]);
  d[2] = make_ushort4(o[8], o[9], o[10], o[11]);
  __syncthreads();
  float4* dst = (float4*)(A + (size_t)blockIdx.x * 256 * 12);
  const float4* s = (const float4*)sb;
  dst[tid] = s[tid];
  if (tid < 128) dst[256 + tid] = s[256 + tid];
}

// ---- B prep (K-major, coalesced): tile 32i x 32o through LDS ---------------
// Bt[o][i*12+n] = mean + eps*exp(0.5*lv); slot 11 = W; KL partial per block.
#define BROW 392   // LDS row stride in ushorts: 32*12 + 8 pad (4-way banks max)
__global__ __launch_bounds__(256) void prep_B_kernel(const float* __restrict__ mean,
    const float* __restrict__ lv, const float* __restrict__ W,
    const float* __restrict__ eps, unsigned short* __restrict__ Bt,
    float* __restrict__ partial) {
  __shared__ unsigned short sb[32 * BROW];   // 25088 B
  __shared__ float wsum[4];
  const int tid = threadIdx.x;
  const int i0 = (blockIdx.x >> 5) * 32;
  const int o0 = (blockIdx.x & 31) * 32;
  float klp = 0.f;
#pragma unroll
  for (int pp = 0; pp < 4; pp++) {
    const int p  = pp * 256 + tid;
    const int il = p >> 5;          // 0..31
    const int ol = p & 31;          // consecutive lanes -> consecutive o (read coalesce)
    const int gi = i0 + il, go = o0 + ol;
    const size_t base = ((size_t)gi * 1024 + go) * DP1;
    unsigned short o16[12];
#pragma unroll
    for (int n = 0; n < DP1; n++) {
      float m = mean[base + n];
      float l = lv[base + n];
      float e = eps[base + n];
      float sd = __expf(0.5f * l);
      o16[n] = f2bf(fmaf(e, sd, m));
      klp += sd * sd + m * m - 1.f - l;   // exp(l) == sd^2
    }
    o16[11] = f2bf(W[(size_t)gi * 1024 + go]);
    ushort4* d = (ushort4*)&sb[ol * BROW + il * 12];   // transposed store, 8B aligned
    d[0] = make_ushort4(o16[0], o16[1], o16[2],  o16[3]);
    d[1] = make_ushort4(o16[4], o16[5], o16[6],  o16[7]);
    d[2] = make_ushort4(o16[8], o16[9], o16[10], o16[11]);
  }
#pragma unroll
  for (int off = 32; off > 0; off >>= 1) klp += __shfl_down(klp, off, 64);
  if ((tid & 63) == 0) wsum[tid >> 6] = klp;
  __syncthreads();
  if (tid == 0) partial[blockIdx.x] = wsum[0] + wsum[1] + wsum[2] + wsum[3];
  // phase 2: write 32 o-rows x 768 B, fully coalesced (1536 x 16B chunks)
#pragma unroll
  for (int cc = 0; cc < 6; cc++) {
    const int c   = cc * 256 + tid;
    const int row = c / 48;
    const int off = c - row * 48;
    float4 v = *(const float4*)((const char*)sb + row * (BROW * 2) + off * 16);
    *(float4*)((char*)Bt + (size_t)(o0 + row) * (KDIM * 2) + (size_t)i0 * 24 + off * 16) = v;
  }
}

__global__ __launch_bounds__(256) void reduce_kl_kernel(const float* __restrict__ partial,
                                                        float* __restrict__ kl_out) {
  __shared__ float wsum[4];
  const int tid = threadIdx.x;
  float s = 0.f;
  for (int idx = tid; idx < 1024; idx += 256) s += partial[idx];
#pragma unroll
  for (int off = 32; off > 0; off >>= 1) s += __shfl_down(s, off, 64);
  if ((tid & 63) == 0) wsum[tid >> 6] = s;
  __syncthreads();
  if (tid == 0) kl_out[0] = 0.5f * (wsum[0] + wsum[1] + wsum[2] + wsum[3]);
}

// ---------------- GEMM: C = A(MxK) * Bt(NxK)^T, bf16 MFMA 16x16x32 ----------
// 64x128 tile, 128 threads (2 waves), grid 1024 -> 4 blocks/CU.
// XCD swizzle: 8 blocks sharing an A-panel land on one XCD (panel fits 4MB L2).
__global__ __launch_bounds__(128) void gemm_kernel(const unsigned short* __restrict__ A,
    const unsigned short* __restrict__ Bt, float* __restrict__ C) {
  __shared__ unsigned short As[64 * BK];    // 4 KB
  __shared__ unsigned short Bs[128 * BK];   // 8 KB
  const int tid  = threadIdx.x;
  const int lane = tid & 63;
  const int wid  = tid >> 6;
  const int bid  = blockIdx.x;
  // bid%8 = XCD (heuristic). Per XCD: slots s=bid>>3; n = s&7 (fast), m-group slow
  // -> the 8 co-resident slots with the same m share one A-panel on one XCD.
  const int mpanel = (bid & 7) * 16 + (bid >> 6);   // 0..127
  const int npanel = (bid >> 3) & 7;                // 0..7
  const int bm0 = mpanel * 64;
  const int bn0 = npanel * 128;
  const int wn  = wid * 64;
  const int q   = lane >> 4;
  const int r   = lane & 15;

  float4v acc[4][4];
#pragma unroll
  for (int a = 0; a < 4; a++)
#pragma unroll
    for (int b = 0; b < 4; b++) acc[a][b] = (float4v){0.f, 0.f, 0.f, 0.f};

  // staging: 768 x 16B chunks (256 A + 512 B), 6 per thread
  const int c0 = tid, c1 = tid + 128;                              // As chunks
  const int d0 = tid, d1 = tid + 128, d2 = tid + 256, d3 = tid + 384;  // Bs chunks
  const char* Ab = (const char*)A;
  const char* Bb = (const char*)Bt;
  const size_t gA0 = (size_t)(bm0 + (c0 >> 2)) * (KDIM * 2) + (size_t)(c0 & 3) * 16;
  const size_t gA1 = (size_t)(bm0 + (c1 >> 2)) * (KDIM * 2) + (size_t)(c1 & 3) * 16;
  const size_t gB0 = (size_t)(bn0 + (d0 >> 2)) * (KDIM * 2) + (size_t)(d0 & 3) * 16;
  const size_t gB1 = (size_t)(bn0 + (d1 >> 2)) * (KDIM * 2) + (size_t)(d1 & 3) * 16;
  const size_t gB2 = (size_t)(bn0 + (d2 >> 2)) * (KDIM * 2) + (size_t)(d2 & 3) * 16;
  const size_t gB3 = (size_t)(bn0 + (d3 >> 2)) * (KDIM * 2) + (size_t)(d3 & 3) * 16;
  char* lA = (char*)As;
  char* lB = (char*)Bs;

  for (int k0 = 0; k0 < KDIM; k0 += BK) {
    const size_t kb = (size_t)k0 * 2;
    __builtin_amdgcn_global_load_lds((gptr_t)(Ab + gA0 + kb), (lptr_t)(lA + c0 * 16), 16, 0, 0);
    __builtin_amdgcn_global_load_lds((gptr_t)(Ab + gA1 + kb), (lptr_t)(lA + c1 * 16), 16, 0, 0);
    __builtin_amdgcn_global_load_lds((gptr_t)(Bb + gB0 + kb), (lptr_t)(lB + d0 * 16), 16, 0, 0);
    __builtin_amdgcn_global_load_lds((gptr_t)(Bb + gB1 + kb), (lptr_t)(lB + d1 * 16), 16, 0, 0);
    __builtin_amdgcn_global_load_lds((gptr_t)(Bb + gB2 + kb), (lptr_t)(lB + d2 * 16), 16, 0, 0);
    __builtin_amdgcn_global_load_lds((gptr_t)(Bb + gB3 + kb), (lptr_t)(lB + d3 * 16), 16, 0, 0);
    __syncthreads();

    short8 af[4], bg[4];
#pragma unroll
    for (int t = 0; t < 4; t++) {
      af[t] = *(const short8*)(lA + (t * 16 + r) * 64 + q * 16);
      bg[t] = *(const short8*)(lB + (wn + t * 16 + r) * 64 + q * 16);
    }
#pragma unroll
    for (int mt = 0; mt < 4; mt++)
#pragma unroll
      for (int nt = 0; nt < 4; nt++)
        acc[mt][nt] = __builtin_amdgcn_mfma_f32_16x16x32_bf16(af[mt], bg[nt], acc[mt][nt], 0, 0, 0);
    __syncthreads();
  }

  float* Cb = C + (size_t)bm0 * NDIM + bn0 + wn;
#pragma unroll
  for (int mt = 0; mt < 4; mt++)
#pragma unroll
    for (int nt = 0; nt < 4; nt++)
#pragma unroll
      for (int v = 0; v < 4; v++)
        Cb[(size_t)(mt * 16 + q * 4 + v) * NDIM + (nt * 16 + r)] = acc[mt][nt][v];
}

extern "C" void kernel_launch(void* const* d_in, const int* in_sizes, int n_in,
                              void* d_out, int out_size, void* d_ws, size_t ws_size,
                              hipStream_t stream) {
  const float* x    = (const float*)d_in[0];   // [8192,1024]
  const float* mean = (const float*)d_in[1];   // [1024,1024,11]
  const float* lv   = (const float*)d_in[2];   // [1024,1024,11]
  const float* W    = (const float*)d_in[3];   // [1024,1024]
  const float* eps  = (const float*)d_in[4];   // [1,1024,1024,11]
  float* out = (float*)d_out;                  // [8192*1024] + [1] kl

  unsigned short* A  = (unsigned short*)d_ws;              // 192 MB
  unsigned short* Bt = A + (size_t)MDIM * KDIM;            // 24 MB
  float* kl = out + (size_t)MDIM * NDIM;
  // KL partials live in the head of d_out; GEMM overwrites them afterwards.
  float* partial = out;

  prep_A_kernel<<<MDIM * FIN / 256, 256, 0, stream>>>(x, A);
  prep_B_kernel<<<(FIN / 32) * (NDIM / 32), 256, 0, stream>>>(mean, lv, W, eps, Bt, partial);
  reduce_kl_kernel<<<1, 256, 0, stream>>>(partial, kl);
  gemm_kernel<<<(MDIM / 64) * (NDIM / 128), 128, 0, stream>>>(A, Bt, out);
}

// Round 5
// 561.503 us; speedup vs baseline: 1.2889x; 1.0044x over previous
//
#include <hip/hip_runtime.h>

#define MDIM 8192
#define NDIM 1024
#define FIN  1024
#define DP1  11
#define KDIM 12288   // FIN * 12  (11 chebyshev + 1 linear slot per feature)
#define BK 32
#define KHALF 6144

typedef __attribute__((ext_vector_type(8))) short short8;
typedef __attribute__((ext_vector_type(4))) float float4v;

typedef const __attribute__((address_space(1))) unsigned int* gptr_t;
typedef __attribute__((address_space(3))) unsigned int* lptr_t;

__device__ __forceinline__ unsigned short f2bf(float f) {
  unsigned int u = __float_as_uint(f);
  u += 0x7FFFu + ((u >> 16) & 1u);   // round-to-nearest-even
  return (unsigned short)(u >> 16);
}

// fast tanh via hardware exp: tanh(x) = 1 - 2/(e^{2x}+1); inf-safe at both ends
__device__ __forceinline__ float fast_tanh(float x) {
  float e = __expf(2.f * x);
  return 1.f - 2.f / (e + 1.f);
}

// ---- A prep: A[b][i*12+n] = T_n(tanh(x)), slot 11 = x; 4 elems/thread ------
__global__ __launch_bounds__(256) void prep_A_kernel(const float4* __restrict__ x4,
                                                     unsigned short* __restrict__ A) {
  __shared__ unsigned short sb[256 * 48];   // 24 KB staging
  const int tid = threadIdx.x;
  float4 xv = x4[(size_t)blockIdx.x * 256 + tid];
  const float xe[4] = {xv.x, xv.y, xv.z, xv.w};
#pragma unroll
  for (int e = 0; e < 4; e++) {
    float t = fast_tanh(xe[e]);
    unsigned short o[12];
    o[0] = 0x3F80u;          // 1.0f
    o[1] = f2bf(t);
    float tm2 = 1.f, tm1 = t;
#pragma unroll
    for (int n = 2; n <= 10; n++) {
      float cur = 2.f * t * tm1 - tm2;
      o[n] = f2bf(cur);
      tm2 = tm1; tm1 = cur;
    }
    o[11] = f2bf(xe[e]);
    ushort4* d = (ushort4*)&sb[tid * 48 + e * 12];
    d[0] = make_ushort4(o[0], o[1], o[2],  o[3]);
    d[1] = make_ushort4(o[4], o[5], o[6],  o[7]);
    d[2] = make_ushort4(o[8], o[9], o[10], o[11]);
  }
  __syncthreads();
  // 24576 B = 1536 x 16B chunks, fully coalesced
  float4* dst = (float4*)(A + (size_t)blockIdx.x * 1024 * 12);
  const float4* s = (const float4*)sb;
#pragma unroll
  for (int c = 0; c < 6; c++) dst[c * 256 + tid] = s[c * 256 + tid];
}

// ---- B prep (K-major, coalesced): tile 32i x 32o through LDS ---------------
#define BROW 392   // LDS row stride in ushorts: 32*12 + 8 pad
__global__ __launch_bounds__(256) void prep_B_kernel(const float* __restrict__ mean,
    const float* __restrict__ lv, const float* __restrict__ W,
    const float* __restrict__ eps, unsigned short* __restrict__ Bt,
    float* __restrict__ partial) {
  __shared__ unsigned short sb[32 * BROW];   // 25088 B
  __shared__ float wsum[4];
  const int tid = threadIdx.x;
  const int i0 = (blockIdx.x >> 5) * 32;
  const int o0 = (blockIdx.x & 31) * 32;
  float klp = 0.f;
#pragma unroll
  for (int pp = 0; pp < 4; pp++) {
    const int p  = pp * 256 + tid;
    const int il = p >> 5;
    const int ol = p & 31;
    const int gi = i0 + il, go = o0 + ol;
    const size_t base = ((size_t)gi * 1024 + go) * DP1;
    unsigned short o16[12];
#pragma unroll
    for (int n = 0; n < DP1; n++) {
      float m = mean[base + n];
      float l = lv[base + n];
      float e = eps[base + n];
      float sd = __expf(0.5f * l);
      o16[n] = f2bf(fmaf(e, sd, m));
      klp += sd * sd + m * m - 1.f - l;   // exp(l) == sd^2
    }
    o16[11] = f2bf(W[(size_t)gi * 1024 + go]);
    ushort4* d = (ushort4*)&sb[ol * BROW + il * 12];
    d[0] = make_ushort4(o16[0], o16[1], o16[2],  o16[3]);
    d[1] = make_ushort4(o16[4], o16[5], o16[6],  o16[7]);
    d[2] = make_ushort4(o16[8], o16[9], o16[10], o16[11]);
  }
#pragma unroll
  for (int off = 32; off > 0; off >>= 1) klp += __shfl_down(klp, off, 64);
  if ((tid & 63) == 0) wsum[tid >> 6] = klp;
  __syncthreads();
  if (tid == 0) partial[blockIdx.x] = wsum[0] + wsum[1] + wsum[2] + wsum[3];
#pragma unroll
  for (int cc = 0; cc < 6; cc++) {
    const int c   = cc * 256 + tid;
    const int row = c / 48;
    const int off = c - row * 48;
    float4 v = *(const float4*)((const char*)sb + row * (BROW * 2) + off * 16);
    *(float4*)((char*)Bt + (size_t)(o0 + row) * (KDIM * 2) + (size_t)i0 * 24 + off * 16) = v;
  }
}

__global__ __launch_bounds__(256) void reduce_kl_kernel(const float* __restrict__ partial,
                                                        float* __restrict__ kl_out) {
  __shared__ float wsum[4];
  const int tid = threadIdx.x;
  float s = 0.f;
  for (int idx = tid; idx < 1024; idx += 256) s += partial[idx];
#pragma unroll
  for (int off = 32; off > 0; off >>= 1) s += __shfl_down(s, off, 64);
  if ((tid & 63) == 0) wsum[tid >> 6] = s;
  __syncthreads();
  if (tid == 0) kl_out[0] = 0.5f * (wsum[0] + wsum[1] + wsum[2] + wsum[3]);
}

// ---------------- GEMM: C += A(MxK) * Bt(NxK)^T, split-K x2 -----------------
// 128x128 tile, 256 threads, 4 waves; grid 1024 -> 4 blocks/CU, 4 waves/SIMD.
// XCD mapping: n-panel = bid&7 (B-panel L2-resident per XCD); A via L3.
__global__ __launch_bounds__(256, 4) void gemm_kernel(const unsigned short* __restrict__ A,
    const unsigned short* __restrict__ Bt, float* __restrict__ C) {
  __shared__ unsigned short As[128 * BK];   // 8 KB
  __shared__ unsigned short Bs[128 * BK];   // 8 KB
  const int tid  = threadIdx.x;
  const int lane = tid & 63;
  const int wid  = tid >> 6;
  const int bid  = blockIdx.x;
  const int bn0  = (bid & 7) * 128;        // XCD-affine n-panel
  const int s    = bid >> 3;               // 0..127
  const int bm0  = (s & 63) * 128;
  const int kh   = s >> 6;                 // 0..1 split-K half
  const int wm   = (wid >> 1) * 64;
  const int wn   = (wid & 1) * 64;
  const int q    = lane >> 4;
  const int r    = lane & 15;

  float4v acc[4][4];
#pragma unroll
  for (int a = 0; a < 4; a++)
#pragma unroll
    for (int b = 0; b < 4; b++) acc[a][b] = (float4v){0.f, 0.f, 0.f, 0.f};

  const int f0 = tid, f1 = tid + 256;      // 512 x 16B chunks per 8KB tile
  const char* gA = (const char*)(A  + (size_t)bm0 * KDIM);
  const char* gB = (const char*)(Bt + (size_t)bn0 * KDIM);
  const size_t oA0 = (size_t)(f0 >> 2) * (KDIM * 2) + (size_t)(f0 & 3) * 16;
  const size_t oA1 = (size_t)(f1 >> 2) * (KDIM * 2) + (size_t)(f1 & 3) * 16;
  char* ldsA = (char*)As;
  char* ldsB = (char*)Bs;

  const int kend = kh * KHALF + KHALF;
  for (int k0 = kh * KHALF; k0 < kend; k0 += BK) {
    const size_t kb = (size_t)k0 * 2;
    __builtin_amdgcn_global_load_lds((gptr_t)(gA + oA0 + kb), (lptr_t)(ldsA + f0 * 16), 16, 0, 0);
    __builtin_amdgcn_global_load_lds((gptr_t)(gA + oA1 + kb), (lptr_t)(ldsA + f1 * 16), 16, 0, 0);
    __builtin_amdgcn_global_load_lds((gptr_t)(gB + oA0 + kb), (lptr_t)(ldsB + f0 * 16), 16, 0, 0);
    __builtin_amdgcn_global_load_lds((gptr_t)(gB + oA1 + kb), (lptr_t)(ldsB + f1 * 16), 16, 0, 0);
    __syncthreads();

    short8 af[4], bg[4];
#pragma unroll
    for (int t = 0; t < 4; t++) {
      af[t] = *(const short8*)(ldsA + ((wm + t * 16 + r) * 64 + q * 16));
      bg[t] = *(const short8*)(ldsB + ((wn + t * 16 + r) * 64 + q * 16));
    }
#pragma unroll
    for (int mt = 0; mt < 4; mt++)
#pragma unroll
      for (int nt = 0; nt < 4; nt++)
        acc[mt][nt] = __builtin_amdgcn_mfma_f32_16x16x32_bf16(af[mt], bg[nt], acc[mt][nt], 0, 0, 0);
    __syncthreads();
  }

  float* Cb = C + (size_t)(bm0 + wm) * NDIM + (bn0 + wn);
#pragma unroll
  for (int mt = 0; mt < 4; mt++)
#pragma unroll
    for (int nt = 0; nt < 4; nt++)
#pragma unroll
      for (int v = 0; v < 4; v++)
        atomicAdd(&Cb[(size_t)(mt * 16 + q * 4 + v) * NDIM + (nt * 16 + r)], acc[mt][nt][v]);
}

extern "C" void kernel_launch(void* const* d_in, const int* in_sizes, int n_in,
                              void* d_out, int out_size, void* d_ws, size_t ws_size,
                              hipStream_t stream) {
  const float* x    = (const float*)d_in[0];   // [8192,1024]
  const float* mean = (const float*)d_in[1];   // [1024,1024,11]
  const float* lv   = (const float*)d_in[2];   // [1024,1024,11]
  const float* W    = (const float*)d_in[3];   // [1024,1024]
  const float* eps  = (const float*)d_in[4];   // [1,1024,1024,11]
  float* out = (float*)d_out;                  // [8192*1024] + [1] kl

  unsigned short* A  = (unsigned short*)d_ws;              // 192 MB
  unsigned short* Bt = A + (size_t)MDIM * KDIM;            // 24 MB
  float* kl = out + (size_t)MDIM * NDIM;
  float* partial = out;   // KL partials in d_out head; cleared before GEMM

  prep_A_kernel<<<MDIM * FIN / 1024, 256, 0, stream>>>((const float4*)x, A);
  prep_B_kernel<<<(FIN / 32) * (NDIM / 32), 256, 0, stream>>>(mean, lv, W, eps, Bt, partial);
  reduce_kl_kernel<<<1, 256, 0, stream>>>(partial, kl);
  hipMemsetAsync(out, 0, (size_t)MDIM * NDIM * sizeof(float), stream);
  gemm_kernel<<<2 * (MDIM / 128) * (NDIM / 128), 256, 0, stream>>>(A, Bt, out);
}

// Round 6
// 480.405 us; speedup vs baseline: 1.5064x; 1.1688x over previous
//
#include <hip/hip_runtime.h>

#define MDIM 8192
#define NDIM 1024
#define FIN  1024
#define DP1  11
#define KDIM 12288   // FIN * 12
#define BM 128
#define BN 128
#define BKB 192      // K-bytes per LDS row (96 bf16 = 8 features x 12)
#define ITERS 64     // 6144 k per split-K half / 96

typedef __attribute__((ext_vector_type(8))) short short8;
typedef __attribute__((ext_vector_type(4))) float float4v;
typedef const __attribute__((address_space(1))) unsigned int* gptr_t;
typedef __attribute__((address_space(3))) unsigned int* lptr_t;

// pack two fp32 -> bf16x2 (RNE) in 5 VALU ops via v_perm
__device__ __forceinline__ unsigned int pk2(float a, float b) {
  unsigned int ua = __float_as_uint(a), ub = __float_as_uint(b);
  ua += 0x7FFFu + ((ua >> 16) & 1u);
  ub += 0x7FFFu + ((ub >> 16) & 1u);
  return __builtin_amdgcn_perm(ub, ua, 0x07060302);  // [b.hi16 : a.hi16]
}

__device__ __forceinline__ float fast_tanh(float x) {
  float e = __expf(2.f * x);
  return 1.f - 2.f / (e + 1.f);
}

// ---- B prep: one i-row per block; coalesced reads; Bt[o][i*12+n]; KL partial
__global__ __launch_bounds__(256) void prep_B_kernel(const float4* __restrict__ mean4,
    const float4* __restrict__ lv4, const float* __restrict__ W,
    const float4* __restrict__ eps4, unsigned short* __restrict__ Bt,
    float* __restrict__ partial) {
  __shared__ float coeff[11264];   // 1024 o x 11 n, 45 KB
  __shared__ float wsum[4];
  const int tid = threadIdx.x;
  const int i = blockIdx.x;
  const size_t b4 = (size_t)i * 2816;
  float klp = 0.f;
#pragma unroll
  for (int k = 0; k < 11; k++) {
    const int idx = k * 256 + tid;
    float4 m = mean4[b4 + idx];
    float4 l = lv4[b4 + idx];
    float4 e = eps4[b4 + idx];
    float s0 = __expf(0.5f * l.x), s1 = __expf(0.5f * l.y);
    float s2 = __expf(0.5f * l.z), s3 = __expf(0.5f * l.w);
    float4 c;
    c.x = fmaf(e.x, s0, m.x); c.y = fmaf(e.y, s1, m.y);
    c.z = fmaf(e.z, s2, m.z); c.w = fmaf(e.w, s3, m.w);
    klp += (s0 * s0 + m.x * m.x - 1.f - l.x) + (s1 * s1 + m.y * m.y - 1.f - l.y)
         + (s2 * s2 + m.z * m.z - 1.f - l.z) + (s3 * s3 + m.w * m.w - 1.f - l.w);
    ((float4*)coeff)[idx] = c;
  }
#pragma unroll
  for (int off = 32; off > 0; off >>= 1) klp += __shfl_down(klp, off, 64);
  if ((tid & 63) == 0) wsum[tid >> 6] = klp;
  __syncthreads();   // coeff visible + wsum ready
  if (tid == 0) partial[i] = wsum[0] + wsum[1] + wsum[2] + wsum[3];
  float4 w4 = ((const float4*)(W + (size_t)i * 1024))[tid];
  const float we[4] = {w4.x, w4.y, w4.z, w4.w};
#pragma unroll
  for (int j = 0; j < 4; j++) {
    const int o = tid * 4 + j;
    const float* cp = &coeff[o * DP1];
    unsigned int u0 = pk2(cp[0], cp[1]);
    unsigned int u1 = pk2(cp[2], cp[3]);
    unsigned int u2 = pk2(cp[4], cp[5]);
    unsigned int u3 = pk2(cp[6], cp[7]);
    unsigned int u4 = pk2(cp[8], cp[9]);
    unsigned int u5 = pk2(cp[10], we[j]);
    char* dst = (char*)Bt + (size_t)o * (KDIM * 2) + (size_t)i * 24;
    ((uint2*)dst)[0] = make_uint2(u0, u1);
    ((uint2*)dst)[1] = make_uint2(u2, u3);
    ((uint2*)dst)[2] = make_uint2(u4, u5);
  }
}

__global__ __launch_bounds__(256) void reduce_kl_kernel(const float* __restrict__ partial,
                                                        float* __restrict__ kl_out) {
  __shared__ float wsum[4];
  const int tid = threadIdx.x;
  float s = 0.f;
  for (int idx = tid; idx < 1024; idx += 256) s += partial[idx];
#pragma unroll
  for (int off = 32; off > 0; off >>= 1) s += __shfl_down(s, off, 64);
  if ((tid & 63) == 0) wsum[tid >> 6] = s;
  __syncthreads();
  if (tid == 0) kl_out[0] = 0.5f * (wsum[0] + wsum[1] + wsum[2] + wsum[3]);
}

// ---- Fused GEMM: A-tile computed on the fly from x; B DMA-staged; split-K x2
__global__ __launch_bounds__(256, 3) void gemm_kernel(const float* __restrict__ x,
    const unsigned short* __restrict__ Bt, float* __restrict__ C) {
  __shared__ unsigned short As[BM * 96];   // 24576 B
  __shared__ unsigned short Bs[BN * 96];   // 24576 B
  const int tid  = threadIdx.x;
  const int lane = tid & 63;
  const int wid  = tid >> 6;
  const int bid  = blockIdx.x;
  const int bn0  = (bid & 7) * BN;         // XCD-affine n-panel
  const int s_   = bid >> 3;
  const int bm0  = (s_ & 63) * BM;
  const int kh   = s_ >> 6;                // split-K half
  const int wm   = (wid >> 1) * 64;
  const int wn   = (wid & 1) * 64;
  const int q    = lane >> 4;
  const int r    = lane & 15;

  float4v acc[4][4];
#pragma unroll
  for (int a = 0; a < 4; a++)
#pragma unroll
    for (int b = 0; b < 4; b++) acc[a][b] = (float4v){0.f, 0.f, 0.f, 0.f};

  // B staging: 1536 chunks of 16B, 6 per thread (offsets constant per thread)
  int gofs[6], lofs[6];
#pragma unroll
  for (int j = 0; j < 6; j++) {
    const int c = tid + j * 256;
    const int rw = c / 12, of = c - rw * 12;
    gofs[j] = (bn0 + rw) * (KDIM * 2) + kh * 12288 + of * 16;
    lofs[j] = c * 16;
  }
  // A compute: thread -> (row, half); features kh*512 + it*8 + half*4 + 0..3
  const int arow = tid >> 1, half = tid & 1;
  const float* xrow = x + (size_t)(bm0 + arow) * FIN + kh * 512 + half * 4;
  const int awb = arow * BKB + half * 0;   // row byte base
  const int asw = arow & 3;                // XOR chunk swizzle
  char* lA = (char*)As;
  char* lB = (char*)Bs;
  const char* gB = (const char*)Bt;

  float4 xv = *(const float4*)xrow;
  for (int it = 0; it < ITERS; it++) {
    const int kb = it * BKB;
#pragma unroll
    for (int j = 0; j < 6; j++)
      __builtin_amdgcn_global_load_lds((gptr_t)(gB + (size_t)(gofs[j] + kb)),
                                       (lptr_t)(lB + lofs[j]), 16, 0, 0);
    // two feature-pairs -> 2x 3 chunks (keeps register liveness low)
    const float xe[4] = {xv.x, xv.y, xv.z, xv.w};
#pragma unroll
    for (int pr = 0; pr < 2; pr++) {
      unsigned int pk[12];
#pragma unroll
      for (int j = 0; j < 2; j++) {
        const float xs = xe[pr * 2 + j];
        const float t = fast_tanh(xs);
        const float t2 = 2.f * t;
        const float T2 = t2 * t - 1.f;
        const float T3 = t2 * T2 - t;
        const float T4 = t2 * T3 - T2;
        const float T5 = t2 * T4 - T3;
        const float T6 = t2 * T5 - T4;
        const float T7 = t2 * T6 - T5;
        const float T8 = t2 * T7 - T6;
        const float T9 = t2 * T8 - T7;
        const float T10 = t2 * T9 - T8;
        pk[j * 6 + 0] = pk2(1.f, t);
        pk[j * 6 + 1] = pk2(T2, T3);
        pk[j * 6 + 2] = pk2(T4, T5);
        pk[j * 6 + 3] = pk2(T6, T7);
        pk[j * 6 + 4] = pk2(T8, T9);
        pk[j * 6 + 5] = pk2(T10, xs);
      }
#pragma unroll
      for (int m = 0; m < 3; m++) {
        const int p = (half * 6 + pr * 3 + m) ^ asw;
        *(int4*)(lA + awb + p * 16) =
            make_int4(pk[4 * m], pk[4 * m + 1], pk[4 * m + 2], pk[4 * m + 3]);
      }
    }
    const int itn = (it < ITERS - 1) ? it + 1 : it;
    float4 xn = *(const float4*)(xrow + itn * 8);   // prefetch next x
    __syncthreads();   // A writes visible; B DMA drained (vmcnt0)
#pragma unroll
    for (int s = 0; s < 3; s++) {
      short8 af[4], bg[4];
#pragma unroll
      for (int t = 0; t < 4; t++) {
        const int ar = wm + t * 16 + r;
        const int ac = 4 * s + (q ^ (r & 3));
        af[t] = *(const short8*)(lA + ar * BKB + ac * 16);
        const int br = wn + t * 16 + r;
        bg[t] = *(const short8*)(lB + br * BKB + (4 * s + q) * 16);
      }
#pragma unroll
      for (int mt = 0; mt < 4; mt++)
#pragma unroll
        for (int nt = 0; nt < 4; nt++)
          acc[mt][nt] = __builtin_amdgcn_mfma_f32_16x16x32_bf16(af[mt], bg[nt], acc[mt][nt], 0, 0, 0);
    }
    __syncthreads();   // reads done before next iter's writes
    xv = xn;
  }

  float* Cb = C + (size_t)(bm0 + wm) * NDIM + (bn0 + wn);
#pragma unroll
  for (int mt = 0; mt < 4; mt++)
#pragma unroll
    for (int nt = 0; nt < 4; nt++)
#pragma unroll
      for (int v = 0; v < 4; v++)
        atomicAdd(&Cb[(size_t)(mt * 16 + q * 4 + v) * NDIM + (nt * 16 + r)], acc[mt][nt][v]);
}

extern "C" void kernel_launch(void* const* d_in, const int* in_sizes, int n_in,
                              void* d_out, int out_size, void* d_ws, size_t ws_size,
                              hipStream_t stream) {
  const float* x    = (const float*)d_in[0];   // [8192,1024]
  const float* mean = (const float*)d_in[1];   // [1024,1024,11]
  const float* lv   = (const float*)d_in[2];   // [1024,1024,11]
  const float* W    = (const float*)d_in[3];   // [1024,1024]
  const float* eps  = (const float*)d_in[4];   // [1,1024,1024,11]
  float* out = (float*)d_out;                  // [8192*1024] + [1] kl

  unsigned short* Bt = (unsigned short*)d_ws;  // 1024 x 12288 bf16 = 24 MB
  float* kl = out + (size_t)MDIM * NDIM;
  float* partial = out;   // KL partials in d_out head; overwritten by GEMM

  prep_B_kernel<<<FIN, 256, 0, stream>>>((const float4*)mean, (const float4*)lv,
                                         W, (const float4*)eps, Bt, partial);
  reduce_kl_kernel<<<1, 256, 0, stream>>>(partial, kl);
  hipMemsetAsync(out, 0, (size_t)MDIM * NDIM * sizeof(float), stream);
  gemm_kernel<<<2 * (MDIM / BM) * (NDIM / BN), 256, 0, stream>>>(x, Bt, out);
}